// Round 9
// baseline (1870.546 us; speedup 1.0000x reference)
//
#include <hip/hip_runtime.h>
#include <hip/hip_bf16.h>

// ---------------------------------------------------------------------------
// spec_ln: spectral graph network forward.
//  * EdgeConv == P[i] + max_{src} Q[src] -> dense GEMM + flip-uint atomic-max.
//  * bf16 MFMA 16x16x32, f32 accum. B operands pre-packed in fragment-lane
//    order and read DIRECTLY from global (L2-resident) -> no LDS, no barriers
//    in the GEMM inner loop.
//  * Features in concatenated layout (xfeat N x 960, sfeat K x 640).
//  * Per-level x/s kernel pairs fused into single launches.
// ---------------------------------------------------------------------------

typedef __attribute__((ext_vector_type(8))) short bf16x8;
typedef __attribute__((ext_vector_type(4))) float f32x4;

#define DEVFN __device__ __forceinline__

constexpr int NN   = 50000;
constexpr int KKn  = 1024;
constexpr int EEe  = 200000;
constexpr int ESn  = 16384;
constexpr int NPAD = 50048;   // 782 * 64
constexpr int NKB  = 1564;    // NPAD / 32

DEVFN short f2bf(float v) {                      // f32 -> bf16 bits, RNE
  unsigned b = __float_as_uint(v);
  unsigned r = (b + 0x7FFFu + ((b >> 16) & 1u)) >> 16;
  return (short)r;
}
DEVFN float lrelu(float v) { return v >= 0.f ? v : 0.01f * v; }
DEVFN float wsum64(float v) {
#pragma unroll
  for (int m = 32; m; m >>= 1) v += __shfl_xor(v, m, 64);
  return v;
}
DEVFN float ln64(float v, float g, float b) {
  float mu  = wsum64(v) * 0.015625f;
  float d   = v - mu;
  float var = wsum64(d * d) * 0.015625f;
  return d * rsqrtf(var + 1e-5f) * g + b;
}

// --- u -> bf16 copy + bf16 transpose, 64x64 tiles, vectorized ---------------
__global__ void transpose_u_k(const float* __restrict__ u, short* __restrict__ ub,
                              short* __restrict__ ut) {
  __shared__ unsigned short tile[64][66];   // [n_local][k_local], +2 pad
  const int kt  = blockIdx.x;               // 16 k-tiles
  const int nt0 = blockIdx.y;               // 782 n-tiles
  const int tx = threadIdx.x & 15, ty = threadIdx.x >> 4;  // 16 x 16
  const int kbase = kt * 64;
#pragma unroll
  for (int r = 0; r < 64; r += 16) {
    int nl = ty + r;
    int n  = nt0 * 64 + nl;
    float4 v = {0.f, 0.f, 0.f, 0.f};
    if (n < NN) v = *(const float4*)(u + (long)n * 1024 + kbase + tx * 4);
    ushort4 w;
    w.x = (unsigned short)f2bf(v.x); w.y = (unsigned short)f2bf(v.y);
    w.z = (unsigned short)f2bf(v.z); w.w = (unsigned short)f2bf(v.w);
    if (n < NN) *(ushort4*)(ub + (long)n * 1024 + kbase + tx * 4) = w;
    tile[nl][tx * 4 + 0] = w.x; tile[nl][tx * 4 + 1] = w.y;
    tile[nl][tx * 4 + 2] = w.z; tile[nl][tx * 4 + 3] = w.w;
  }
  __syncthreads();
#pragma unroll
  for (int r = 0; r < 64; r += 16) {
    int kl = ty + r;
    int k  = kbase + kl;
    int n0 = nt0 * 64 + tx * 4;
    ushort4 w;
    w.x = tile[tx * 4 + 0][kl]; w.y = tile[tx * 4 + 1][kl];
    w.z = tile[tx * 4 + 2][kl]; w.w = tile[tx * 4 + 3][kl];
    *(ushort4*)(ut + (long)k * NPAD + n0) = w;
  }
}

// --- pack a bf16 matrix slice into MFMA-B fragment-lane order ---------------
__global__ void pack_b_k(const short* __restrict__ src, int lds_, int coloff,
                         int Kred, int kb_total, int C, short* __restrict__ dst) {
  long t = (long)blockIdx.x * 256 + threadIdx.x;
  long total = (long)kb_total * 32 * C;
  if (t >= total) return;
  int k = (int)(t / C);
  int c = (int)(t - (long)k * C);
  short v = (k < Kred) ? src[(long)k * lds_ + coloff + c] : (short)0;
  long pa = (long)(k >> 5) * (32 * C) + ((c >> 4) << 9) + (((k >> 3) & 3) << 7)
          + ((c & 15) << 3) + (k & 7);
  dst[pa] = v;
}

// --- conv weight (64 x 2F f32) -> packed bf16 Wcat (F x 128) ----------------
__global__ void pack_wcat_k(const float* __restrict__ W, int F, short* __restrict__ dst) {
  int t = blockIdx.x * 256 + threadIdx.x;
  if (t >= F * 128) return;
  int f = t >> 7, c = t & 127;
  float v = (c < 64) ? (W[c * 2 * F + f] - W[c * 2 * F + F + f])
                     : W[(c - 64) * 2 * F + F + f];
  long pa = (long)(f >> 5) * (32 * 128) + ((c >> 4) << 9) + (((f >> 3) & 3) << 7)
          + ((c & 15) << 3) + (f & 7);
  dst[pa] = f2bf(v);
}

// --- d1_w (64 x 960 f32) -> packed bf16 (960 x 64) -------------------------
__global__ void pack_d1t_k(const float* __restrict__ W, short* __restrict__ dst) {
  int t = blockIdx.x * 256 + threadIdx.x;
  if (t >= 960 * 64) return;
  int f = t >> 6, c = t & 63;
  float v = W[c * 960 + f];
  long pa = (long)(f >> 5) * (32 * 64) + ((c >> 4) << 9) + (((f >> 3) & 3) << 7)
          + ((c & 15) << 3) + (f & 7);
  dst[pa] = f2bf(v);
}

// --- GEMM body: out(M x C) = A(M x K, bf16 rowmajor) @ Bpacked --------------
// B-fragments read directly from global (L2-resident) -> no LDS, no barriers.
// EPI 0: f32 store, 1: bf16 store, 2: f32 atomicAdd (split-K)
template <int NT, int EPI>
DEVFN void gemm_body(const short* __restrict__ A, int lda,
                     const short* __restrict__ Bp,
                     void* __restrict__ outp, int ldo, int coloff,
                     int M, int mtile, int kb0, int kb1) {
  const int lane = threadIdx.x & 63;
  const int wave = threadIdx.x >> 6;
  const int row  = mtile * 64 + wave * 16 + (lane & 15);
  const long arow = (long)min(row, M - 1) * lda + ((lane >> 4) * 8);
  const short* bl = Bp + lane * 8;
  f32x4 acc[NT];
#pragma unroll
  for (int t = 0; t < NT; ++t) acc[t] = (f32x4){0.f, 0.f, 0.f, 0.f};

  for (int kb = kb0; kb < kb1; ++kb) {
    bf16x8 a = *(const bf16x8*)(A + arow + (long)kb * 32);
    const short* bsrc = bl + (long)kb * (NT * 512);
#pragma unroll
    for (int t = 0; t < NT; ++t) {
      bf16x8 b = *(const bf16x8*)(bsrc + t * 512);
      acc[t] = __builtin_amdgcn_mfma_f32_16x16x32_bf16(a, b, acc[t], 0, 0, 0);
    }
  }
  const int cb = lane & 15;
  const int rbase = mtile * 64 + wave * 16 + ((lane >> 4) * 4);
#pragma unroll
  for (int t = 0; t < NT; ++t) {
#pragma unroll
    for (int r = 0; r < 4; ++r) {
      int rr = rbase + r;
      if (rr < M) {
        long idx = (long)rr * ldo + coloff + t * 16 + cb;
        if constexpr (EPI == 0)      ((float*)outp)[idx] = acc[t][r];
        else if constexpr (EPI == 1) ((short*)outp)[idx] = f2bf(acc[t][r]);
        else                          atomicAdd((float*)outp + idx, acc[t][r]);
      }
    }
  }
}

template <int NT, int EPI>
__launch_bounds__(256)
__global__ void gemm_k(const short* __restrict__ A, int lda,
                       const short* __restrict__ Bp,
                       void* __restrict__ outp, int ldo, int coloff,
                       int M, int kb_total, int kb_chunk) {
  int kb0 = blockIdx.y * kb_chunk;
  int kb1 = min(kb0 + kb_chunk, kb_total);
  gemm_body<NT, EPI>(A, lda, Bp, outp, ldo, coloff, M, blockIdx.x, kb0, kb1);
}

// fused conv GEMM: x-side (blocks < GX0) + s-side, both f32 out ld=128
template <int NT>
__launch_bounds__(256)
__global__ void gemmx2_k(const short* __restrict__ A0, int lda0,
                         const short* __restrict__ B0, float* out0, int M0, int GX0,
                         const short* __restrict__ A1, int lda1,
                         const short* __restrict__ B1, float* out1, int M1,
                         int kb_total) {
  int b = blockIdx.x;
  if (b < GX0) gemm_body<NT, 0>(A0, lda0, B0, out0, 128, 0, M0, b, 0, kb_total);
  else         gemm_body<NT, 0>(A1, lda1, B1, out1, 128, 0, M1, b - GX0, 0, kb_total);
}

// --- small MLP heads (wave per row, lane = channel) -------------------------
__global__ void mlp_spec_k(const float* __restrict__ e, const float* __restrict__ w1,
                           const float* __restrict__ b1, const float* __restrict__ w2,
                           const float* __restrict__ b2, const float* __restrict__ g,
                           const float* __restrict__ bl, short* __restrict__ feat, int ldf) {
  int t = blockIdx.x * 256 + threadIdx.x;
  int i = t >> 6, lane = t & 63;
  if (i >= KKn) return;
  float ev = e[i];
  float h = lrelu(ev * w1[lane] + b1[lane]);
  h = ln64(h, g[lane], bl[lane]);
  float a = b2[lane];
  for (int j = 0; j < 64; ++j) a += __shfl(h, j, 64) * w2[lane * 64 + j];
  a = lrelu(a); a = ln64(a, g[lane], bl[lane]);
  feat[(long)i * ldf + lane] = f2bf(a);
}

__global__ void mlp_sp_k(const float* __restrict__ x, const float* __restrict__ w1,
                         const float* __restrict__ b1, const float* __restrict__ w2,
                         const float* __restrict__ b2, const float* __restrict__ g,
                         const float* __restrict__ bl, short* __restrict__ feat, int ldf) {
  int t = blockIdx.x * 256 + threadIdx.x;
  int i = t >> 6, lane = t & 63;
  if (i >= NN) return;
  float x0 = x[i * 3 + 0], x1 = x[i * 3 + 1], x2 = x[i * 3 + 2];
  float h = x0 * w1[lane * 3 + 0] + x1 * w1[lane * 3 + 1] + x2 * w1[lane * 3 + 2] + b1[lane];
  h = lrelu(h); h = ln64(h, g[lane], bl[lane]);
  float a = b2[lane];
  for (int j = 0; j < 64; ++j) a += __shfl(h, j, 64) * w2[lane * 64 + j];
  a = lrelu(a); a = ln64(a, g[lane], bl[lane]);
  feat[(long)i * ldf + lane] = f2bf(a);
}

// --- edge max: flip-uint atomicMax of Q[src] into mc[dst] -------------------
DEVFN void edge_max_body(const int* __restrict__ ei, int E, const float* __restrict__ PQ,
                         unsigned* __restrict__ mc, int e, int lane) {
  if (e >= E) return;
  int src = ei[e], dst = ei[E + e];
  float v = PQ[(long)src * 128 + 64 + lane];
  unsigned b = __float_as_uint(v);
  unsigned code = b ^ ((unsigned)(((int)b) >> 31) | 0x80000000u);
  atomicMax(mc + (long)dst * 64 + lane, code);
}

__global__ void edge_max_k(const int* __restrict__ ei, int E, const float* __restrict__ PQ,
                           unsigned* __restrict__ mc) {
  int t = blockIdx.x * 256 + threadIdx.x;
  edge_max_body(ei, E, PQ, mc, t >> 6, t & 63);
}

__global__ void edge_max2_k(const int* __restrict__ ei0, int E0, const float* __restrict__ PQ0,
                            unsigned* __restrict__ mc0, int nb0,
                            const int* __restrict__ ei1, int E1, const float* __restrict__ PQ1,
                            unsigned* __restrict__ mc1) {
  int b = blockIdx.x, w = threadIdx.x >> 6, lane = threadIdx.x & 63;
  if (b < nb0) edge_max_body(ei0, E0, PQ0, mc0, b * 4 + w, lane);
  else         edge_max_body(ei1, E1, PQ1, mc1, (b - nb0) * 4 + w, lane);
}

// --- finish conv: val = (edges? P+bias+maxQ : 0); lrelu; LN; store bf16 -----
DEVFN void segfin_body(const float* __restrict__ PQ, const unsigned* __restrict__ mc,
                       const float* __restrict__ bias, const float* __restrict__ g,
                       const float* __restrict__ bl, short* __restrict__ feat,
                       int ldf, int coloff, int n, int i, int lane) {
  if (i >= n) return;
  unsigned code = mc[(long)i * 64 + lane];
  float v = 0.f;
  if (code) {
    unsigned ub = code ^ ((code & 0x80000000u) ? 0x80000000u : 0xFFFFFFFFu);
    v = PQ[(long)i * 128 + lane] + bias[lane] + __uint_as_float(ub);
  }
  v = lrelu(v);
  v = ln64(v, g[lane], bl[lane]);
  feat[(long)i * ldf + coloff + lane] = f2bf(v);
}

__global__ void segfin_k(const float* __restrict__ PQ, const unsigned* __restrict__ mc,
                         const float* __restrict__ bias, const float* __restrict__ g,
                         const float* __restrict__ bl, short* __restrict__ feat,
                         int ldf, int coloff, int n) {
  int t = blockIdx.x * 256 + threadIdx.x;
  segfin_body(PQ, mc, bias, g, bl, feat, ldf, coloff, n, t >> 6, t & 63);
}

__global__ void segfin2_k(const float* __restrict__ PQ0, const unsigned* __restrict__ mc0,
                          const float* __restrict__ bias0, short* __restrict__ feat0,
                          int co0, int n0, int nb0,
                          const float* __restrict__ PQ1, const unsigned* __restrict__ mc1,
                          const float* __restrict__ bias1, short* __restrict__ feat1,
                          int co1, int n1,
                          const float* __restrict__ g, const float* __restrict__ bl) {
  int b = blockIdx.x, w = threadIdx.x >> 6, lane = threadIdx.x & 63;
  if (b < nb0) segfin_body(PQ0, mc0, bias0, g, bl, feat0, 960, co0, n0, b * 4 + w, lane);
  else         segfin_body(PQ1, mc1, bias1, g, bl, feat1, 640, co1, n1, (b - nb0) * 4 + w, lane);
}

// --- Zscr f32 (K x C) -> bf16 into sfeat slice ------------------------------
__global__ void zconv_k(const float* __restrict__ Z, short* __restrict__ feat,
                        int C, int coloff) {
  int t = blockIdx.x * 256 + threadIdx.x;
  if (t >= KKn * C) return;
  int k = t / C, c = t - k * C;
  feat[(long)k * 640 + coloff + c] = f2bf(Z[t]);
}

// --- head: lrelu+LN on d1 output, then @ d2^T + b ---------------------------
__global__ void final_k(const float* __restrict__ H, const float* __restrict__ d1b,
                        const float* __restrict__ d2w, const float* __restrict__ d2b,
                        const float* __restrict__ g, const float* __restrict__ bl,
                        float* __restrict__ out) {
  int t = blockIdx.x * 256 + threadIdx.x;
  int i = t >> 6, lane = t & 63;
  if (i >= NN) return;
  float v = H[(long)i * 64 + lane] + d1b[lane];
  v = lrelu(v);
  v = ln64(v, g[lane], bl[lane]);
  int c = lane & 31;
  int jbase = (lane >> 5) * 32;
  float acc = 0.f;
#pragma unroll
  for (int j = 0; j < 32; ++j)
    acc += __shfl(v, jbase + j, 64) * d2w[c * 64 + jbase + j];
  acc += __shfl_down(acc, 32, 64);
  if (lane < 32) out[(long)i * 32 + c] = acc + d2b[c];
}

// ===========================================================================
extern "C" void kernel_launch(void* const* d_in, const int* in_sizes, int n_in,
                              void* d_out, int out_size, void* d_ws, size_t ws_size,
                              hipStream_t stream) {
  const float* x    = (const float*)d_in[0];
  const float* u    = (const float*)d_in[1];
  const float* e    = (const float*)d_in[2];
  const int*   ei   = (const int*)d_in[3];
  const int*   sei  = (const int*)d_in[4];
  const float* se1w = (const float*)d_in[5];  const float* se1b = (const float*)d_in[6];
  const float* se2w = (const float*)d_in[7];  const float* se2b = (const float*)d_in[8];
  const float* sp1w = (const float*)d_in[9];  const float* sp1b = (const float*)d_in[10];
  const float* sp2w = (const float*)d_in[11]; const float* sp2b = (const float*)d_in[12];
  const float* c1w = (const float*)d_in[13];  const float* c1b = (const float*)d_in[14];
  const float* c2w = (const float*)d_in[15];  const float* c2b = (const float*)d_in[16];
  const float* c3w = (const float*)d_in[17];  const float* c3b = (const float*)d_in[18];
  const float* c5w = (const float*)d_in[19];  const float* c5b = (const float*)d_in[20];
  const float* c6w = (const float*)d_in[21];  const float* c6b = (const float*)d_in[22];
  const float* c7w = (const float*)d_in[23];  const float* c7b = (const float*)d_in[24];
  const float* c8w = (const float*)d_in[25];  const float* c8b = (const float*)d_in[26];
  const float* d1w = (const float*)d_in[27];  const float* d1b = (const float*)d_in[28];
  const float* d2w = (const float*)d_in[29];  const float* d2b = (const float*)d_in[30];
  const float* lng = (const float*)d_in[31];  const float* lnb = (const float*)d_in[32];

  char* ws = (char*)d_ws;
  size_t off = 0;
  auto alloc = [&](size_t bytes) -> void* {
    void* p = ws + off;
    off = (off + bytes + 255) & ~(size_t)255;
    return p;
  };
  short* u_bf  = (short*)alloc((size_t)NN * 1024 * 2);         // 102.4 MB
  short* uT    = (short*)alloc((size_t)KKn * NPAD * 2);        // 102.5 MB
  short* xfeat = (short*)alloc((size_t)NN * 960 * 2);          //  96.0 MB
  short* sfeat = (short*)alloc((size_t)KKn * 640 * 2);
  float* PQx   = (float*)alloc((size_t)NN * 128 * 4);          //  25.6 MB (alias Hbuf)
  float* PQs   = (float*)alloc((size_t)KKn * 128 * 4);
  char* zbase = ws + off;                                      // zero region
  unsigned* mx  = (unsigned*)alloc((size_t)NN * 64 * 4);       //  12.8 MB
  unsigned* ms  = (unsigned*)alloc((size_t)KKn * 64 * 4);
  float* Zs0 = (float*)alloc((size_t)KKn * 64 * 4);
  float* Zs1 = (float*)alloc((size_t)KKn * 128 * 4);
  float* Zs2 = (float*)alloc((size_t)KKn * 192 * 4);
  size_t zbytes = (size_t)((ws + off) - zbase);
  short* ypack = (short*)alloc((size_t)KKn * 256 * 2);
  short* zpack = (short*)alloc((size_t)NPAD * 192 * 2);        //  19.2 MB
  short* wc1 = (short*)alloc(64  * 128 * 2);
  short* wc2 = (short*)alloc(192 * 128 * 2);
  short* wc3 = (short*)alloc(384 * 128 * 2);
  short* wc5 = (short*)alloc(64  * 128 * 2);
  short* wc6 = (short*)alloc(192 * 128 * 2);
  short* wc7 = (short*)alloc(384 * 128 * 2);
  short* wc8 = (short*)alloc(640 * 128 * 2);
  short* d1tp = (short*)alloc(960 * 64 * 2);
  float* Hbuf = PQx;  // alias: PQx last read by segfin(level4) before d1 GEMM

  const size_t MXB = (size_t)NN * 64 * 4;
  const size_t MSB = (size_t)KKn * 64 * 4;

  // ---- setup ----
  hipMemsetAsync(zbase, 0, zbytes, stream);
  transpose_u_k<<<dim3(16, 782), 256, 0, stream>>>(u, u_bf, uT);
  pack_wcat_k<<<32,  256, 0, stream>>>(c1w, 64,  wc1);
  pack_wcat_k<<<96,  256, 0, stream>>>(c2w, 192, wc2);
  pack_wcat_k<<<192, 256, 0, stream>>>(c3w, 384, wc3);
  pack_wcat_k<<<32,  256, 0, stream>>>(c5w, 64,  wc5);
  pack_wcat_k<<<96,  256, 0, stream>>>(c6w, 192, wc6);
  pack_wcat_k<<<192, 256, 0, stream>>>(c7w, 384, wc7);
  pack_wcat_k<<<320, 256, 0, stream>>>(c8w, 640, wc8);
  pack_d1t_k<<<240, 256, 0, stream>>>(d1w, d1tp);
  mlp_spec_k<<<256,   256, 0, stream>>>(e, se1w, se1b, se2w, se2b, lng, lnb, sfeat, 640);
  mlp_sp_k<<<12500,   256, 0, stream>>>(x, sp1w, sp1b, sp2w, sp2b, lng, lnb, xfeat, 960);

  const int GX = (NN + 63) / 64;  // 782 M-tiles for N-row GEMMs

  // ---- level 1 ----
  gemmx2_k<8><<<GX + 16, 256, 0, stream>>>(xfeat, 960, wc5, PQx, NN, GX,
                                           sfeat, 640, wc1, PQs, KKn, 2);
  edge_max2_k<<<50000 + 4096, 256, 0, stream>>>(ei, EEe, PQx, mx, 50000, sei, ESn, PQs, ms);
  segfin2_k<<<12500 + 256, 256, 0, stream>>>(PQx, mx, c5b, xfeat, 64, NN, 12500,
                                             PQs, ms, c1b, sfeat, 64, KKn, lng, lnb);
  pack_b_k<<<256, 256, 0, stream>>>(sfeat, 640, 0, KKn, 32, 64, ypack);
  gemm_k<4, 1><<<dim3(GX, 1), 256, 0, stream>>>(u_bf, 1024, ypack, xfeat, 960, 128, NN, 32, 32);
  pack_b_k<<<12512, 256, 0, stream>>>(xfeat, 960, 0, NN, NKB, 64, zpack);
  gemm_k<4, 2><<<dim3(16, 16), 256, 0, stream>>>(uT, NPAD, zpack, Zs0, 64, 0, KKn, NKB, 98);
  zconv_k<<<256, 256, 0, stream>>>(Zs0, sfeat, 64, 128);

  // ---- level 2 ----
  hipMemsetAsync(mx, 0, MXB, stream);
  hipMemsetAsync(ms, 0, MSB, stream);
  gemmx2_k<8><<<GX + 16, 256, 0, stream>>>(xfeat, 960, wc6, PQx, NN, GX,
                                           sfeat, 640, wc2, PQs, KKn, 6);
  edge_max2_k<<<50000 + 4096, 256, 0, stream>>>(ei, EEe, PQx, mx, 50000, sei, ESn, PQs, ms);
  segfin2_k<<<12500 + 256, 256, 0, stream>>>(PQx, mx, c6b, xfeat, 192, NN, 12500,
                                             PQs, ms, c2b, sfeat, 192, KKn, lng, lnb);
  pack_b_k<<<512, 256, 0, stream>>>(sfeat, 640, 64, KKn, 32, 128, ypack);
  gemm_k<8, 1><<<dim3(GX, 1), 256, 0, stream>>>(u_bf, 1024, ypack, xfeat, 960, 256, NN, 32, 32);
  pack_b_k<<<25024, 256, 0, stream>>>(xfeat, 960, 64, NN, NKB, 128, zpack);
  gemm_k<8, 2><<<dim3(16, 16), 256, 0, stream>>>(uT, NPAD, zpack, Zs1, 128, 0, KKn, NKB, 98);
  zconv_k<<<512, 256, 0, stream>>>(Zs1, sfeat, 128, 256);

  // ---- level 3 ----
  hipMemsetAsync(mx, 0, MXB, stream);
  hipMemsetAsync(ms, 0, MSB, stream);
  gemmx2_k<8><<<GX + 16, 256, 0, stream>>>(xfeat, 960, wc7, PQx, NN, GX,
                                           sfeat, 640, wc3, PQs, KKn, 12);
  edge_max2_k<<<50000 + 4096, 256, 0, stream>>>(ei, EEe, PQx, mx, 50000, sei, ESn, PQs, ms);
  segfin2_k<<<12500 + 256, 256, 0, stream>>>(PQx, mx, c7b, xfeat, 384, NN, 12500,
                                             PQs, ms, c3b, sfeat, 384, KKn, lng, lnb);
  pack_b_k<<<768, 256, 0, stream>>>(sfeat, 640, 192, KKn, 32, 192, ypack);
  gemm_k<12, 1><<<dim3(GX, 1), 256, 0, stream>>>(u_bf, 1024, ypack, xfeat, 960, 448, NN, 32, 32);
  pack_b_k<<<37536, 256, 0, stream>>>(xfeat, 960, 192, NN, NKB, 192, zpack);
  gemm_k<12, 2><<<dim3(16, 16), 256, 0, stream>>>(uT, NPAD, zpack, Zs2, 192, 0, KKn, NKB, 98);
  zconv_k<<<768, 256, 0, stream>>>(Zs2, sfeat, 192, 448);

  // ---- level 4 (spatial only) ----
  hipMemsetAsync(mx, 0, MXB, stream);
  gemm_k<8, 0><<<dim3(GX, 1), 256, 0, stream>>>(xfeat, 960, wc8, PQx, 128, 0, NN, 20, 20);
  edge_max_k<<<50000, 256, 0, stream>>>(ei, EEe, PQx, mx);
  segfin_k<<<12500, 256, 0, stream>>>(PQx, mx, c8b, lng, lnb, xfeat, 960, 640, NN);
  pack_b_k<<<1024, 256, 0, stream>>>(sfeat, 640, 384, KKn, 32, 256, ypack);
  gemm_k<16, 1><<<dim3(GX, 1), 256, 0, stream>>>(u_bf, 1024, ypack, xfeat, 960, 704, NN, 32, 32);

  // ---- head ----
  gemm_k<4, 0><<<dim3(GX, 1), 256, 0, stream>>>(xfeat, 960, d1tp, Hbuf, 64, 0, NN, 30, 30);
  final_k<<<12500, 256, 0, stream>>>(Hbuf, d1b, d2w, d2b, lng, lnb, (float*)d_out);

  (void)in_sizes; (void)n_in; (void)out_size; (void)ws_size;
}

// Round 15
// 1360.258 us; speedup vs baseline: 1.3751x; 1.3751x over previous
//
#include <hip/hip_runtime.h>
#include <hip/hip_bf16.h>

// ---------------------------------------------------------------------------
// spec_ln: spectral graph network forward.
//  * EdgeConv == P[i] + max_{src} Q[src] -> dense GEMM + flip-uint atomic-max.
//  * bf16 MFMA 16x16x32, f32 accum. B pre-packed in fragment-lane order,
//    cooperatively staged through LDS each K-block (round-5 proven structure;
//    round-9's direct-global B-reads were latency-serialized: 294us, MfmaUtil
//    2.6%, VGPR=36 -> single-b-buffer serial loads).
//  * Features in concatenated layout (xfeat N x 960, sfeat K x 640).
//  * Per-level x/s kernel pairs fused into single launches.
// ---------------------------------------------------------------------------

typedef __attribute__((ext_vector_type(8))) short bf16x8;
typedef __attribute__((ext_vector_type(4))) float f32x4;

#define DEVFN __device__ __forceinline__

constexpr int NN   = 50000;
constexpr int KKn  = 1024;
constexpr int EEe  = 200000;
constexpr int ESn  = 16384;
constexpr int NPAD = 50048;   // 782 * 64
constexpr int NKB  = 1564;    // NPAD / 32

DEVFN short f2bf(float v) {                      // f32 -> bf16 bits, RNE
  unsigned b = __float_as_uint(v);
  unsigned r = (b + 0x7FFFu + ((b >> 16) & 1u)) >> 16;
  return (short)r;
}
DEVFN float lrelu(float v) { return v >= 0.f ? v : 0.01f * v; }
DEVFN float wsum64(float v) {
#pragma unroll
  for (int m = 32; m; m >>= 1) v += __shfl_xor(v, m, 64);
  return v;
}
DEVFN float ln64(float v, float g, float b) {
  float mu  = wsum64(v) * 0.015625f;
  float d   = v - mu;
  float var = wsum64(d * d) * 0.015625f;
  return d * rsqrtf(var + 1e-5f) * g + b;
}

// --- u -> bf16 copy + bf16 transpose, 64x64 tiles, vectorized ---------------
__global__ void transpose_u_k(const float* __restrict__ u, short* __restrict__ ub,
                              short* __restrict__ ut) {
  __shared__ unsigned short tile[64][66];   // [n_local][k_local], +2 pad
  const int kt  = blockIdx.x;               // 16 k-tiles
  const int nt0 = blockIdx.y;               // 782 n-tiles
  const int tx = threadIdx.x & 15, ty = threadIdx.x >> 4;  // 16 x 16
  const int kbase = kt * 64;
#pragma unroll
  for (int r = 0; r < 64; r += 16) {
    int nl = ty + r;
    int n  = nt0 * 64 + nl;
    float4 v = {0.f, 0.f, 0.f, 0.f};
    if (n < NN) v = *(const float4*)(u + (long)n * 1024 + kbase + tx * 4);
    ushort4 w;
    w.x = (unsigned short)f2bf(v.x); w.y = (unsigned short)f2bf(v.y);
    w.z = (unsigned short)f2bf(v.z); w.w = (unsigned short)f2bf(v.w);
    if (n < NN) *(ushort4*)(ub + (long)n * 1024 + kbase + tx * 4) = w;
    tile[nl][tx * 4 + 0] = w.x; tile[nl][tx * 4 + 1] = w.y;
    tile[nl][tx * 4 + 2] = w.z; tile[nl][tx * 4 + 3] = w.w;
  }
  __syncthreads();
#pragma unroll
  for (int r = 0; r < 64; r += 16) {
    int kl = ty + r;
    int k  = kbase + kl;
    int n0 = nt0 * 64 + tx * 4;
    ushort4 w;
    w.x = tile[tx * 4 + 0][kl]; w.y = tile[tx * 4 + 1][kl];
    w.z = tile[tx * 4 + 2][kl]; w.w = tile[tx * 4 + 3][kl];
    *(ushort4*)(ut + (long)k * NPAD + n0) = w;
  }
}

// --- pack a bf16 matrix slice into MFMA-B fragment-lane order ---------------
__global__ void pack_b_k(const short* __restrict__ src, int lds_, int coloff,
                         int Kred, int kb_total, int C, short* __restrict__ dst) {
  long t = (long)blockIdx.x * 256 + threadIdx.x;
  long total = (long)kb_total * 32 * C;
  if (t >= total) return;
  int k = (int)(t / C);
  int c = (int)(t - (long)k * C);
  short v = (k < Kred) ? src[(long)k * lds_ + coloff + c] : (short)0;
  long pa = (long)(k >> 5) * (32 * C) + ((c >> 4) << 9) + (((k >> 3) & 3) << 7)
          + ((c & 15) << 3) + (k & 7);
  dst[pa] = v;
}

// --- conv weight (64 x 2F f32) -> packed bf16 Wcat (F x 128) ----------------
__global__ void pack_wcat_k(const float* __restrict__ W, int F, short* __restrict__ dst) {
  int t = blockIdx.x * 256 + threadIdx.x;
  if (t >= F * 128) return;
  int f = t >> 7, c = t & 127;
  float v = (c < 64) ? (W[c * 2 * F + f] - W[c * 2 * F + F + f])
                     : W[(c - 64) * 2 * F + F + f];
  long pa = (long)(f >> 5) * (32 * 128) + ((c >> 4) << 9) + (((f >> 3) & 3) << 7)
          + ((c & 15) << 3) + (f & 7);
  dst[pa] = f2bf(v);
}

// --- d1_w (64 x 960 f32) -> packed bf16 (960 x 64) -------------------------
__global__ void pack_d1t_k(const float* __restrict__ W, short* __restrict__ dst) {
  int t = blockIdx.x * 256 + threadIdx.x;
  if (t >= 960 * 64) return;
  int f = t >> 6, c = t & 63;
  float v = W[c * 960 + f];
  long pa = (long)(f >> 5) * (32 * 64) + ((c >> 4) << 9) + (((f >> 3) & 3) << 7)
          + ((c & 15) << 3) + (f & 7);
  dst[pa] = f2bf(v);
}

// --- GEMM body: out(M x C) = A(M x K, bf16 rowmajor) @ Bpacked --------------
// B cooperatively staged global -> LDS each K-block (bulk loads in flight),
// MFMAs read LDS. EPI 0: f32 store, 1: bf16 store, 2: f32 atomicAdd (split-K)
template <int NT, int EPI>
DEVFN void gemm_body(short* bsm, const short* __restrict__ A, int lda,
                     const short* __restrict__ Bp,
                     void* __restrict__ outp, int ldo, int coloff,
                     int M, int mtile, int kb0, int kb1) {
  constexpr int C = NT * 16;
  const int tid  = threadIdx.x;
  const int lane = tid & 63;
  const int wave = tid >> 6;
  const int row  = mtile * 64 + wave * 16 + (lane & 15);
  const long arow = (long)min(row, M - 1) * lda + ((lane >> 4) * 8);
  f32x4 acc[NT];
#pragma unroll
  for (int t = 0; t < NT; ++t) acc[t] = (f32x4){0.f, 0.f, 0.f, 0.f};

  for (int kb = kb0; kb < kb1; ++kb) {
    const short* bsrc = Bp + (long)kb * (32 * C);
    bf16x8 tmp[NT / 4];
#pragma unroll
    for (int r = 0; r < NT / 4; ++r)
      tmp[r] = *(const bf16x8*)(bsrc + (r * 256 + tid) * 8);
    bf16x8 a = *(const bf16x8*)(A + arow + (long)kb * 32);
    __syncthreads();
#pragma unroll
    for (int r = 0; r < NT / 4; ++r)
      *(bf16x8*)(bsm + (r * 256 + tid) * 8) = tmp[r];
    __syncthreads();
#pragma unroll
    for (int t = 0; t < NT; ++t) {
      bf16x8 b = *(const bf16x8*)(bsm + t * 512 + lane * 8);
      acc[t] = __builtin_amdgcn_mfma_f32_16x16x32_bf16(a, b, acc[t], 0, 0, 0);
    }
  }
  const int cb = lane & 15;
  const int rbase = mtile * 64 + wave * 16 + ((lane >> 4) * 4);
#pragma unroll
  for (int t = 0; t < NT; ++t) {
#pragma unroll
    for (int r = 0; r < 4; ++r) {
      int rr = rbase + r;
      if (rr < M) {
        long idx = (long)rr * ldo + coloff + t * 16 + cb;
        if constexpr (EPI == 0)      ((float*)outp)[idx] = acc[t][r];
        else if constexpr (EPI == 1) ((short*)outp)[idx] = f2bf(acc[t][r]);
        else                          atomicAdd((float*)outp + idx, acc[t][r]);
      }
    }
  }
}

template <int NT, int EPI>
__launch_bounds__(256)
__global__ void gemm_k(const short* __restrict__ A, int lda,
                       const short* __restrict__ Bp,
                       void* __restrict__ outp, int ldo, int coloff,
                       int M, int kb_total, int kb_chunk) {
  __shared__ short bsm[32 * NT * 16];
  int kb0 = blockIdx.y * kb_chunk;
  int kb1 = min(kb0 + kb_chunk, kb_total);
  gemm_body<NT, EPI>(bsm, A, lda, Bp, outp, ldo, coloff, M, blockIdx.x, kb0, kb1);
}

// fused conv GEMM: x-side (blocks < GX0) + s-side, both f32 out ld=128
template <int NT>
__launch_bounds__(256)
__global__ void gemmx2_k(const short* __restrict__ A0, int lda0,
                         const short* __restrict__ B0, float* out0, int M0, int GX0,
                         const short* __restrict__ A1, int lda1,
                         const short* __restrict__ B1, float* out1, int M1,
                         int kb_total) {
  __shared__ short bsm[32 * NT * 16];
  int b = blockIdx.x;
  if (b < GX0) gemm_body<NT, 0>(bsm, A0, lda0, B0, out0, 128, 0, M0, b, 0, kb_total);
  else         gemm_body<NT, 0>(bsm, A1, lda1, B1, out1, 128, 0, M1, b - GX0, 0, kb_total);
}

// --- small MLP heads (wave per row, lane = channel) -------------------------
__global__ void mlp_spec_k(const float* __restrict__ e, const float* __restrict__ w1,
                           const float* __restrict__ b1, const float* __restrict__ w2,
                           const float* __restrict__ b2, const float* __restrict__ g,
                           const float* __restrict__ bl, short* __restrict__ feat, int ldf) {
  int t = blockIdx.x * 256 + threadIdx.x;
  int i = t >> 6, lane = t & 63;
  if (i >= KKn) return;
  float ev = e[i];
  float h = lrelu(ev * w1[lane] + b1[lane]);
  h = ln64(h, g[lane], bl[lane]);
  float a = b2[lane];
  for (int j = 0; j < 64; ++j) a += __shfl(h, j, 64) * w2[lane * 64 + j];
  a = lrelu(a); a = ln64(a, g[lane], bl[lane]);
  feat[(long)i * ldf + lane] = f2bf(a);
}

__global__ void mlp_sp_k(const float* __restrict__ x, const float* __restrict__ w1,
                         const float* __restrict__ b1, const float* __restrict__ w2,
                         const float* __restrict__ b2, const float* __restrict__ g,
                         const float* __restrict__ bl, short* __restrict__ feat, int ldf) {
  int t = blockIdx.x * 256 + threadIdx.x;
  int i = t >> 6, lane = t & 63;
  if (i >= NN) return;
  float x0 = x[i * 3 + 0], x1 = x[i * 3 + 1], x2 = x[i * 3 + 2];
  float h = x0 * w1[lane * 3 + 0] + x1 * w1[lane * 3 + 1] + x2 * w1[lane * 3 + 2] + b1[lane];
  h = lrelu(h); h = ln64(h, g[lane], bl[lane]);
  float a = b2[lane];
  for (int j = 0; j < 64; ++j) a += __shfl(h, j, 64) * w2[lane * 64 + j];
  a = lrelu(a); a = ln64(a, g[lane], bl[lane]);
  feat[(long)i * ldf + lane] = f2bf(a);
}

// --- edge max: flip-uint atomicMax of Q[src] into mc[dst] -------------------
DEVFN void edge_max_body(const int* __restrict__ ei, int E, const float* __restrict__ PQ,
                         unsigned* __restrict__ mc, int e, int lane) {
  if (e >= E) return;
  int src = ei[e], dst = ei[E + e];
  float v = PQ[(long)src * 128 + 64 + lane];
  unsigned b = __float_as_uint(v);
  unsigned code = b ^ ((unsigned)(((int)b) >> 31) | 0x80000000u);
  atomicMax(mc + (long)dst * 64 + lane, code);
}

__global__ void edge_max_k(const int* __restrict__ ei, int E, const float* __restrict__ PQ,
                           unsigned* __restrict__ mc) {
  int t = blockIdx.x * 256 + threadIdx.x;
  edge_max_body(ei, E, PQ, mc, t >> 6, t & 63);
}

__global__ void edge_max2_k(const int* __restrict__ ei0, int E0, const float* __restrict__ PQ0,
                            unsigned* __restrict__ mc0, int nb0,
                            const int* __restrict__ ei1, int E1, const float* __restrict__ PQ1,
                            unsigned* __restrict__ mc1) {
  int b = blockIdx.x, w = threadIdx.x >> 6, lane = threadIdx.x & 63;
  if (b < nb0) edge_max_body(ei0, E0, PQ0, mc0, b * 4 + w, lane);
  else         edge_max_body(ei1, E1, PQ1, mc1, (b - nb0) * 4 + w, lane);
}

// --- finish conv: val = (edges? P+bias+maxQ : 0); lrelu; LN; store bf16 -----
DEVFN void segfin_body(const float* __restrict__ PQ, const unsigned* __restrict__ mc,
                       const float* __restrict__ bias, const float* __restrict__ g,
                       const float* __restrict__ bl, short* __restrict__ feat,
                       int ldf, int coloff, int n, int i, int lane) {
  if (i >= n) return;
  unsigned code = mc[(long)i * 64 + lane];
  float v = 0.f;
  if (code) {
    unsigned ub = code ^ ((code & 0x80000000u) ? 0x80000000u : 0xFFFFFFFFu);
    v = PQ[(long)i * 128 + lane] + bias[lane] + __uint_as_float(ub);
  }
  v = lrelu(v);
  v = ln64(v, g[lane], bl[lane]);
  feat[(long)i * ldf + coloff + lane] = f2bf(v);
}

__global__ void segfin_k(const float* __restrict__ PQ, const unsigned* __restrict__ mc,
                         const float* __restrict__ bias, const float* __restrict__ g,
                         const float* __restrict__ bl, short* __restrict__ feat,
                         int ldf, int coloff, int n) {
  int t = blockIdx.x * 256 + threadIdx.x;
  segfin_body(PQ, mc, bias, g, bl, feat, ldf, coloff, n, t >> 6, t & 63);
}

__global__ void segfin2_k(const float* __restrict__ PQ0, const unsigned* __restrict__ mc0,
                          const float* __restrict__ bias0, short* __restrict__ feat0,
                          int co0, int n0, int nb0,
                          const float* __restrict__ PQ1, const unsigned* __restrict__ mc1,
                          const float* __restrict__ bias1, short* __restrict__ feat1,
                          int co1, int n1,
                          const float* __restrict__ g, const float* __restrict__ bl) {
  int b = blockIdx.x, w = threadIdx.x >> 6, lane = threadIdx.x & 63;
  if (b < nb0) segfin_body(PQ0, mc0, bias0, g, bl, feat0, 960, co0, n0, b * 4 + w, lane);
  else         segfin_body(PQ1, mc1, bias1, g, bl, feat1, 640, co1, n1, (b - nb0) * 4 + w, lane);
}

// --- Zscr f32 (K x C) -> bf16 into sfeat slice ------------------------------
__global__ void zconv_k(const float* __restrict__ Z, short* __restrict__ feat,
                        int C, int coloff) {
  int t = blockIdx.x * 256 + threadIdx.x;
  if (t >= KKn * C) return;
  int k = t / C, c = t - k * C;
  feat[(long)k * 640 + coloff + c] = f2bf(Z[t]);
}

// --- head: lrelu+LN on d1 output, then @ d2^T + b ---------------------------
__global__ void final_k(const float* __restrict__ H, const float* __restrict__ d1b,
                        const float* __restrict__ d2w, const float* __restrict__ d2b,
                        const float* __restrict__ g, const float* __restrict__ bl,
                        float* __restrict__ out) {
  int t = blockIdx.x * 256 + threadIdx.x;
  int i = t >> 6, lane = t & 63;
  if (i >= NN) return;
  float v = H[(long)i * 64 + lane] + d1b[lane];
  v = lrelu(v);
  v = ln64(v, g[lane], bl[lane]);
  int c = lane & 31;
  int jbase = (lane >> 5) * 32;
  float acc = 0.f;
#pragma unroll
  for (int j = 0; j < 32; ++j)
    acc += __shfl(v, jbase + j, 64) * d2w[c * 64 + jbase + j];
  acc += __shfl_down(acc, 32, 64);
  if (lane < 32) out[(long)i * 32 + c] = acc + d2b[c];
}

// ===========================================================================
extern "C" void kernel_launch(void* const* d_in, const int* in_sizes, int n_in,
                              void* d_out, int out_size, void* d_ws, size_t ws_size,
                              hipStream_t stream) {
  const float* x    = (const float*)d_in[0];
  const float* u    = (const float*)d_in[1];
  const float* e    = (const float*)d_in[2];
  const int*   ei   = (const int*)d_in[3];
  const int*   sei  = (const int*)d_in[4];
  const float* se1w = (const float*)d_in[5];  const float* se1b = (const float*)d_in[6];
  const float* se2w = (const float*)d_in[7];  const float* se2b = (const float*)d_in[8];
  const float* sp1w = (const float*)d_in[9];  const float* sp1b = (const float*)d_in[10];
  const float* sp2w = (const float*)d_in[11]; const float* sp2b = (const float*)d_in[12];
  const float* c1w = (const float*)d_in[13];  const float* c1b = (const float*)d_in[14];
  const float* c2w = (const float*)d_in[15];  const float* c2b = (const float*)d_in[16];
  const float* c3w = (const float*)d_in[17];  const float* c3b = (const float*)d_in[18];
  const float* c5w = (const float*)d_in[19];  const float* c5b = (const float*)d_in[20];
  const float* c6w = (const float*)d_in[21];  const float* c6b = (const float*)d_in[22];
  const float* c7w = (const float*)d_in[23];  const float* c7b = (const float*)d_in[24];
  const float* c8w = (const float*)d_in[25];  const float* c8b = (const float*)d_in[26];
  const float* d1w = (const float*)d_in[27];  const float* d1b = (const float*)d_in[28];
  const float* d2w = (const float*)d_in[29];  const float* d2b = (const float*)d_in[30];
  const float* lng = (const float*)d_in[31];  const float* lnb = (const float*)d_in[32];

  char* ws = (char*)d_ws;
  size_t off = 0;
  auto alloc = [&](size_t bytes) -> void* {
    void* p = ws + off;
    off = (off + bytes + 255) & ~(size_t)255;
    return p;
  };
  short* u_bf  = (short*)alloc((size_t)NN * 1024 * 2);         // 102.4 MB
  short* uT    = (short*)alloc((size_t)KKn * NPAD * 2);        // 102.5 MB
  short* xfeat = (short*)alloc((size_t)NN * 960 * 2);          //  96.0 MB
  short* sfeat = (short*)alloc((size_t)KKn * 640 * 2);
  float* PQx   = (float*)alloc((size_t)NN * 128 * 4);          //  25.6 MB (alias Hbuf)
  float* PQs   = (float*)alloc((size_t)KKn * 128 * 4);
  char* zbase = ws + off;                                      // zero region
  unsigned* mx  = (unsigned*)alloc((size_t)NN * 64 * 4);       //  12.8 MB
  unsigned* ms  = (unsigned*)alloc((size_t)KKn * 64 * 4);
  float* Zs0 = (float*)alloc((size_t)KKn * 64 * 4);
  float* Zs1 = (float*)alloc((size_t)KKn * 128 * 4);
  float* Zs2 = (float*)alloc((size_t)KKn * 192 * 4);
  size_t zbytes = (size_t)((ws + off) - zbase);
  short* ypack = (short*)alloc((size_t)KKn * 256 * 2);
  short* zpack = (short*)alloc((size_t)NPAD * 192 * 2);        //  19.2 MB
  short* wc1 = (short*)alloc(64  * 128 * 2);
  short* wc2 = (short*)alloc(192 * 128 * 2);
  short* wc3 = (short*)alloc(384 * 128 * 2);
  short* wc5 = (short*)alloc(64  * 128 * 2);
  short* wc6 = (short*)alloc(192 * 128 * 2);
  short* wc7 = (short*)alloc(384 * 128 * 2);
  short* wc8 = (short*)alloc(640 * 128 * 2);
  short* d1tp = (short*)alloc(960 * 64 * 2);
  float* Hbuf = PQx;  // alias: PQx last read by segfin(level4) before d1 GEMM

  const size_t MXB = (size_t)NN * 64 * 4;
  const size_t MSB = (size_t)KKn * 64 * 4;

  // ---- setup ----
  hipMemsetAsync(zbase, 0, zbytes, stream);
  transpose_u_k<<<dim3(16, 782), 256, 0, stream>>>(u, u_bf, uT);
  pack_wcat_k<<<32,  256, 0, stream>>>(c1w, 64,  wc1);
  pack_wcat_k<<<96,  256, 0, stream>>>(c2w, 192, wc2);
  pack_wcat_k<<<192, 256, 0, stream>>>(c3w, 384, wc3);
  pack_wcat_k<<<32,  256, 0, stream>>>(c5w, 64,  wc5);
  pack_wcat_k<<<96,  256, 0, stream>>>(c6w, 192, wc6);
  pack_wcat_k<<<192, 256, 0, stream>>>(c7w, 384, wc7);
  pack_wcat_k<<<320, 256, 0, stream>>>(c8w, 640, wc8);
  pack_d1t_k<<<240, 256, 0, stream>>>(d1w, d1tp);
  mlp_spec_k<<<256,   256, 0, stream>>>(e, se1w, se1b, se2w, se2b, lng, lnb, sfeat, 640);
  mlp_sp_k<<<12500,   256, 0, stream>>>(x, sp1w, sp1b, sp2w, sp2b, lng, lnb, xfeat, 960);

  const int GX = (NN + 63) / 64;  // 782 M-tiles for N-row GEMMs

  // ---- level 1 ----
  gemmx2_k<8><<<GX + 16, 256, 0, stream>>>(xfeat, 960, wc5, PQx, NN, GX,
                                           sfeat, 640, wc1, PQs, KKn, 2);
  edge_max2_k<<<50000 + 4096, 256, 0, stream>>>(ei, EEe, PQx, mx, 50000, sei, ESn, PQs, ms);
  segfin2_k<<<12500 + 256, 256, 0, stream>>>(PQx, mx, c5b, xfeat, 64, NN, 12500,
                                             PQs, ms, c1b, sfeat, 64, KKn, lng, lnb);
  pack_b_k<<<256, 256, 0, stream>>>(sfeat, 640, 0, KKn, 32, 64, ypack);
  gemm_k<4, 1><<<dim3(GX, 1), 256, 0, stream>>>(u_bf, 1024, ypack, xfeat, 960, 128, NN, 32, 32);
  pack_b_k<<<12512, 256, 0, stream>>>(xfeat, 960, 0, NN, NKB, 64, zpack);
  gemm_k<4, 2><<<dim3(16, 16), 256, 0, stream>>>(uT, NPAD, zpack, Zs0, 64, 0, KKn, NKB, 98);
  zconv_k<<<256, 256, 0, stream>>>(Zs0, sfeat, 64, 128);

  // ---- level 2 ----
  hipMemsetAsync(mx, 0, MXB, stream);
  hipMemsetAsync(ms, 0, MSB, stream);
  gemmx2_k<8><<<GX + 16, 256, 0, stream>>>(xfeat, 960, wc6, PQx, NN, GX,
                                           sfeat, 640, wc2, PQs, KKn, 6);
  edge_max2_k<<<50000 + 4096, 256, 0, stream>>>(ei, EEe, PQx, mx, 50000, sei, ESn, PQs, ms);
  segfin2_k<<<12500 + 256, 256, 0, stream>>>(PQx, mx, c6b, xfeat, 192, NN, 12500,
                                             PQs, ms, c2b, sfeat, 192, KKn, lng, lnb);
  pack_b_k<<<512, 256, 0, stream>>>(sfeat, 640, 64, KKn, 32, 128, ypack);
  gemm_k<8, 1><<<dim3(GX, 1), 256, 0, stream>>>(u_bf, 1024, ypack, xfeat, 960, 256, NN, 32, 32);
  pack_b_k<<<25024, 256, 0, stream>>>(xfeat, 960, 64, NN, NKB, 128, zpack);
  gemm_k<8, 2><<<dim3(16, 16), 256, 0, stream>>>(uT, NPAD, zpack, Zs1, 128, 0, KKn, NKB, 98);
  zconv_k<<<512, 256, 0, stream>>>(Zs1, sfeat, 128, 256);

  // ---- level 3 ----
  hipMemsetAsync(mx, 0, MXB, stream);
  hipMemsetAsync(ms, 0, MSB, stream);
  gemmx2_k<8><<<GX + 16, 256, 0, stream>>>(xfeat, 960, wc7, PQx, NN, GX,
                                           sfeat, 640, wc3, PQs, KKn, 12);
  edge_max2_k<<<50000 + 4096, 256, 0, stream>>>(ei, EEe, PQx, mx, 50000, sei, ESn, PQs, ms);
  segfin2_k<<<12500 + 256, 256, 0, stream>>>(PQx, mx, c7b, xfeat, 384, NN, 12500,
                                             PQs, ms, c3b, sfeat, 384, KKn, lng, lnb);
  pack_b_k<<<768, 256, 0, stream>>>(sfeat, 640, 192, KKn, 32, 192, ypack);
  gemm_k<12, 1><<<dim3(GX, 1), 256, 0, stream>>>(u_bf, 1024, ypack, xfeat, 960, 448, NN, 32, 32);
  pack_b_k<<<37536, 256, 0, stream>>>(xfeat, 960, 192, NN, NKB, 192, zpack);
  gemm_k<12, 2><<<dim3(16, 16), 256, 0, stream>>>(uT, NPAD, zpack, Zs2, 192, 0, KKn, NKB, 98);
  zconv_k<<<768, 256, 0, stream>>>(Zs2, sfeat, 192, 448);

  // ---- level 4 (spatial only) ----
  hipMemsetAsync(mx, 0, MXB, stream);
  gemm_k<8, 0><<<dim3(GX, 1), 256, 0, stream>>>(xfeat, 960, wc8, PQx, 128, 0, NN, 20, 20);
  edge_max_k<<<50000, 256, 0, stream>>>(ei, EEe, PQx, mx);
  segfin_k<<<12500, 256, 0, stream>>>(PQx, mx, c8b, lng, lnb, xfeat, 960, 640, NN);
  pack_b_k<<<1024, 256, 0, stream>>>(sfeat, 640, 384, KKn, 32, 256, ypack);
  gemm_k<16, 1><<<dim3(GX, 1), 256, 0, stream>>>(u_bf, 1024, ypack, xfeat, 960, 704, NN, 32, 32);

  // ---- head ----
  gemm_k<4, 0><<<dim3(GX, 1), 256, 0, stream>>>(xfeat, 960, d1tp, Hbuf, 64, 0, NN, 30, 30);
  final_k<<<12500, 256, 0, stream>>>(Hbuf, d1b, d2w, d2b, lng, lnb, (float*)d_out);

  (void)in_sizes; (void)n_in; (void)out_size; (void)ws_size;
}